// Round 11
// baseline (153.312 us; speedup 1.0000x reference)
//
#include <hip/hip_runtime.h>
#include <hip/hip_fp8.h>

typedef __attribute__((ext_vector_type(4))) int   i32x4;
typedef __attribute__((ext_vector_type(8))) int   i32x8;
typedef __attribute__((ext_vector_type(16))) float f32x16;

// ---------------------------------------------------------------------------
// Fused slice + convert(f32 -> fp8 e4m3 OCP) + mask-zero for BOTH inputs.
__global__ void conv_kernel(const float* __restrict__ im, const int* __restrict__ iml,
                            const float* __restrict__ ss, const int* __restrict__ sl,
                            unsigned char* __restrict__ Ad, unsigned char* __restrict__ Bd)
{
    int bid = blockIdx.x;
    const float* src; const int* len; unsigned char* dst; int rawL, adj;
    if (bid < 8192) { src = im; len = iml; dst = Ad; rawL = 65; adj = -1; }
    else { bid -= 8192; src = ss; len = sl; dst = Bd; rawL = 67; adj = -3; }
    int m = bid;
    int c = threadIdx.x << 2;
    int b = m >> 6;
    int i = m & 63;
    int lim = len[b] + adj;
    float4 v;
    if (i < lim) {
        v = *(const float4*)(src + ((size_t)(b * rawL + 1 + i) << 10) + c);
    } else {
        v = make_float4(0.f, 0.f, 0.f, 0.f);
    }
    uchar4 o;
    o.x = __hip_cvt_float_to_fp8(v.x, __HIP_SATFINITE, __HIP_E4M3);
    o.y = __hip_cvt_float_to_fp8(v.y, __HIP_SATFINITE, __HIP_E4M3);
    o.z = __hip_cvt_float_to_fp8(v.z, __HIP_SATFINITE, __HIP_E4M3);
    o.w = __hip_cvt_float_to_fp8(v.w, __HIP_SATFINITE, __HIP_E4M3);
    *(uchar4*)(dst + ((size_t)m << 10) + c) = o;
}

// ---------------------------------------------------------------------------
__device__ __forceinline__ void gload_lds16(const void* g, void* l) {
    __builtin_amdgcn_global_load_lds((const __attribute__((address_space(1))) void*)g,
                                     (__attribute__((address_space(3))) void*)l,
                                     16, 0, 0);
}

// Read a 32-byte fp8 operand fragment as two XOR-swizzled b128 granules.
// shufflevector concat of two int4 loads -> encourages clean 2x ds_read_b128.
__device__ __forceinline__ i32x8 rd32(const char* base, int o0) {
    i32x4 a = *(const i32x4*)(base + o0);
    i32x4 b = *(const i32x4*)(base + (o0 ^ 16));
    return __builtin_shufflevector(a, b, 0, 1, 2, 3, 4, 5, 6, 7);
}

// 256x128 tile, BK=64 (fp8: 64B rows), 256 threads = 4 waves (2M x 2N),
// per-wave 128x64 output. LDS 48 KiB (A 2x16K, B 2x8K) -> 2-3 INDEPENDENT
// blocks/CU: cross-block drift overlaps the LDS pipe with the MFMA pipe
// (intra-block barriers serialized them in all 1-block/CU configs).
// One {vmcnt(0); s_barrier} gate per tile; 6 gloads staged right after.
// Swizzle for 64B rows: granule d of row r at position d ^ ((r>>1)&3);
// bank slot (r&1, p) -> all 8 slots distinct per 8-lane group (b128-safe).
// MFMA: mfma_scale_f32_32x32x64_f8f6f4, e4m3, scale=1.0 (E8M0 127).
// C/D layout (r9/r10-verified): col=lane&31, row=(reg&3)+8*(reg>>2)+4*(lane>>5).
__global__ void __launch_bounds__(256) gemm_aggr_kernel(const unsigned char* __restrict__ A,
                                                        const unsigned char* __restrict__ B,
                                                        float* __restrict__ aggr)
{
    __shared__ __align__(16) char As[2][16384];   // 256 rows x 64 B
    __shared__ __align__(16) char Bs[2][8192];    // 128 rows x 64 B

    const int tid  = threadIdx.x;
    const int lane = tid & 63;
    const int wid  = tid >> 6;        // 0..3
    const int wr   = wid >> 1;        // 0..1 : 128-row half of BM=256
    const int wc   = wid & 1;         // 0..1 : 64-col half of BN=128
    const int tm   = blockIdx.y;      // 0..31
    const int tn   = blockIdx.x;      // 0..63

    const int r31 = lane & 31;
    const int g2  = lane >> 5;        // 0..1

    // Staging: round = 64 rows x 64 B = 4 KB = 256 thr x 16 B.
    // LDS dest linear; global source granule pre-swizzled (both-sides XOR).
    const int srow   = tid >> 2;                  // 0..63
    const int schunk = (tid & 3) ^ ((srow >> 1) & 3);
    const unsigned char* gA_t = A + ((size_t)(tm * 256 + srow) << 10) + schunk * 16;
    const unsigned char* gB_t = B + ((size_t)(tn * 128 + srow) << 10) + schunk * 16;

#define STAGE_A(kt, r) gload_lds16(gA_t + (((size_t)(r) * 64) << 10) + (kt) * 64, \
                                   As[(kt) & 1] + (r) * 4096 + tid * 16)
#define STAGE_B(kt, r) gload_lds16(gB_t + (((size_t)(r) * 64) << 10) + (kt) * 64, \
                                   Bs[(kt) & 1] + (r) * 4096 + tid * 16)

    f32x16 acc[4][2];   // [32-row block mi][32-col block ni]
#pragma unroll
    for (int mi = 0; mi < 4; ++mi)
#pragma unroll
        for (int ni = 0; ni < 2; ++ni)
#pragma unroll
            for (int r = 0; r < 16; ++r)
                acc[mi][ni][r] = 0.f;

    // Prologue: stage tile 0 (6 gloads).
    STAGE_A(0, 0); STAGE_A(0, 1); STAGE_A(0, 2); STAGE_A(0, 3);
    STAGE_B(0, 0); STAGE_B(0, 1);

    // o0 is fragment-independent: 32-row strides are 0 mod 4 after >>1.
    const int o0 = ((g2 * 2) ^ ((r31 >> 1) & 3)) * 16;
    const int ArBase = (wr * 128 + r31) * 64;    // + mi*32*64
    const int BrBase = (wc * 64 + r31) * 64;     // + ni*32*64

#define SB __builtin_amdgcn_sched_barrier(0)

#define MFMA2(MI, AF)                                                       \
    __builtin_amdgcn_s_setprio(1);                                          \
    acc[MI][0] = __builtin_amdgcn_mfma_scale_f32_32x32x64_f8f6f4(           \
        AF, bg0, acc[MI][0], 0, 0, 0, 127, 0, 127);                         \
    acc[MI][1] = __builtin_amdgcn_mfma_scale_f32_32x32x64_f8f6f4(           \
        AF, bg1, acc[MI][1], 0, 0, 0, 127, 0, 127);                         \
    __builtin_amdgcn_s_setprio(0);

#pragma unroll 2
    for (int kt = 0; kt < 16; ++kt) {
        const char* Ab = As[kt & 1];
        const char* Bb = Bs[kt & 1];

        // ---- per-tile gate: loads are one full tile old -> near-free ----
        asm volatile("s_waitcnt vmcnt(0)" ::: "memory");
        __builtin_amdgcn_s_barrier();
        SB;
        if (kt < 15) {
            STAGE_A(kt + 1, 0); STAGE_A(kt + 1, 1);
            STAGE_A(kt + 1, 2); STAGE_A(kt + 1, 3);
            STAGE_B(kt + 1, 0); STAGE_B(kt + 1, 1);
        }
        SB;
        i32x8 bg0 = rd32(Bb + BrBase, o0);
        i32x8 bg1 = rd32(Bb + BrBase + 2048, o0);
        i32x8 afA = rd32(Ab + ArBase, o0);
        i32x8 afB = rd32(Ab + ArBase + 2048, o0);
        MFMA2(0, afA)
        afA = rd32(Ab + ArBase + 4096, o0);
        MFMA2(1, afB)
        afB = rd32(Ab + ArBase + 6144, o0);
        MFMA2(2, afA)
        MFMA2(3, afB)
    }
#undef STAGE_A
#undef STAGE_B
#undef MFMA2
#undef SB

    // Fused reduction per 64x64 (b,t) cell (r10-verified layout).
    // C/D: col = lane&31, row = (reg&3) + 8*(reg>>2) + 4*(lane>>5).
#pragma unroll
    for (int h = 0; h < 2; ++h) {
        float cm[2];
#pragma unroll
        for (int ni = 0; ni < 2; ++ni) {
            float m = acc[h * 2][ni][0];
#pragma unroll
            for (int dm = 0; dm < 2; ++dm)
#pragma unroll
                for (int r = 0; r < 16; ++r)
                    m = fmaxf(m, acc[h * 2 + dm][ni][r]);
            m = fmaxf(m, __shfl_xor(m, 32));   // other 16 rows of the 32-row tile
            cm[ni] = m;                        // col max, replicated over lane>>5
        }
        float s = cm[0] + cm[1];
        s += __shfl_xor(s, 1);
        s += __shfl_xor(s, 2);
        s += __shfl_xor(s, 4);
        s += __shfl_xor(s, 8);
        s += __shfl_xor(s, 16);
        if (lane == 0) {
            int b = tm * 4 + wr * 2 + h;
            int t = tn * 2 + wc;
            aggr[b * 128 + t] = s;
        }
    }
}

// ---------------------------------------------------------------------------
__global__ void loss_kernel(const float* __restrict__ aggr, float* __restrict__ out)
{
    __shared__ float red[128];
    const int x = threadIdx.x;
    const float diag = aggr[x * 128 + x];
    float mrow = 0.f, mcol = 0.f;
    for (int y = 0; y < 128; ++y) {
        if (y == x) continue;
        float a_xy = aggr[x * 128 + y];
        float a_yx = aggr[y * 128 + x];
        mrow = fmaxf(mrow, 0.2f + a_xy - diag);
        mcol = fmaxf(mcol, 0.2f + a_yx - diag);
    }
    red[x] = mrow + mcol;
    __syncthreads();
    if (x == 0) {
        float s = 0.f;
        for (int i = 0; i < 128; ++i) s += red[i];
        *out = s;
    }
}

// ---------------------------------------------------------------------------
extern "C" void kernel_launch(void* const* d_in, const int* in_sizes, int n_in,
                              void* d_out, int out_size, void* d_ws, size_t ws_size,
                              hipStream_t stream)
{
    const float* im_set = (const float*)d_in[0];
    const float* s_seq  = (const float*)d_in[1];
    const int*   im_len = (const int*)d_in[2];
    const int*   s_len  = (const int*)d_in[3];
    float* out = (float*)d_out;

    unsigned char* Abf = (unsigned char*)d_ws;                          // 8 MiB
    unsigned char* Bbf = (unsigned char*)d_ws + (8u << 20);             // 8 MiB
    float*         agg = (float*)((char*)d_ws + (16u << 20));           // 64 KiB

    conv_kernel<<<16384, 256, 0, stream>>>(im_set, im_len, s_seq, s_len, Abf, Bbf);

    gemm_aggr_kernel<<<dim3(64, 32), 256, 0, stream>>>(Abf, Bbf, agg);

    loss_kernel<<<1, 128, 0, stream>>>(agg, out);
}

// Round 12
// 108.786 us; speedup vs baseline: 1.4093x; 1.4093x over previous
//
#include <hip/hip_runtime.h>
#include <hip/hip_fp8.h>

typedef __attribute__((ext_vector_type(4))) int   i32x4;
typedef __attribute__((ext_vector_type(8))) int   i32x8;
typedef __attribute__((ext_vector_type(16))) float f32x16;

// ---------------------------------------------------------------------------
// Fused slice + convert(f32 -> fp8 e4m3 OCP) + mask-zero for BOTH inputs.
__global__ void conv_kernel(const float* __restrict__ im, const int* __restrict__ iml,
                            const float* __restrict__ ss, const int* __restrict__ sl,
                            unsigned char* __restrict__ Ad, unsigned char* __restrict__ Bd)
{
    int bid = blockIdx.x;
    const float* src; const int* len; unsigned char* dst; int rawL, adj;
    if (bid < 8192) { src = im; len = iml; dst = Ad; rawL = 65; adj = -1; }
    else { bid -= 8192; src = ss; len = sl; dst = Bd; rawL = 67; adj = -3; }
    int m = bid;
    int c = threadIdx.x << 2;
    int b = m >> 6;
    int i = m & 63;
    int lim = len[b] + adj;
    float4 v;
    if (i < lim) {
        v = *(const float4*)(src + ((size_t)(b * rawL + 1 + i) << 10) + c);
    } else {
        v = make_float4(0.f, 0.f, 0.f, 0.f);
    }
    uchar4 o;
    o.x = __hip_cvt_float_to_fp8(v.x, __HIP_SATFINITE, __HIP_E4M3);
    o.y = __hip_cvt_float_to_fp8(v.y, __HIP_SATFINITE, __HIP_E4M3);
    o.z = __hip_cvt_float_to_fp8(v.z, __HIP_SATFINITE, __HIP_E4M3);
    o.w = __hip_cvt_float_to_fp8(v.w, __HIP_SATFINITE, __HIP_E4M3);
    *(uchar4*)(dst + ((size_t)m << 10) + c) = o;
}

// ---------------------------------------------------------------------------
__device__ __forceinline__ void gload_lds16(const void* g, void* l) {
    __builtin_amdgcn_global_load_lds((const __attribute__((address_space(1))) void*)g,
                                     (__attribute__((address_space(3))) void*)l,
                                     16, 0, 0);
}

// Read a 32-byte fp8 operand fragment as two XOR-swizzled b128 granules.
__device__ __forceinline__ i32x8 rd32(const char* base, int o0) {
    i32x4 a = *(const i32x4*)(base + o0);
    i32x4 b = *(const i32x4*)(base + (o0 ^ 16));
    return __builtin_shufflevector(a, b, 0, 1, 2, 3, 4, 5, 6, 7);
}

// 256x128 tile, BK=64 (fp8: 64B rows), 256 threads = 4 waves (2M x 2N),
// per-wave 128x64 output. LDS 48 KiB. __launch_bounds__(256,2) caps regs at
// 256/wave (128 VGPR + 128 AGPR acc) -> 2 INDEPENDENT blocks/CU; their
// uncorrelated barrier phases overlap one block's LDS bursts with the
// other's MFMA bursts (r11 ran 1 block/CU at 268 regs -> no overlap).
// One {vmcnt(0); s_barrier} gate per tile; 6 gloads staged right after.
// Swizzle (64B rows): granule d of row r at d ^ ((r>>1)&3); pre-swizzled
// global source + swizzled read. MFMA: mfma_scale_f32_32x32x64_f8f6f4,
// e4m3, scale=1.0 (E8M0 127). C/D (r10-verified): col=lane&31,
// row=(reg&3)+8*(reg>>2)+4*(lane>>5).
__global__ void __launch_bounds__(256, 2) gemm_aggr_kernel(const unsigned char* __restrict__ A,
                                                           const unsigned char* __restrict__ B,
                                                           float* __restrict__ aggr)
{
    __shared__ __align__(16) char As[2][16384];   // 256 rows x 64 B
    __shared__ __align__(16) char Bs[2][8192];    // 128 rows x 64 B

    const int tid  = threadIdx.x;
    const int lane = tid & 63;
    const int wid  = tid >> 6;        // 0..3
    const int wr   = wid >> 1;        // 0..1 : 128-row half of BM=256
    const int wc   = wid & 1;         // 0..1 : 64-col half of BN=128
    const int tm   = blockIdx.y;      // 0..31
    const int tn   = blockIdx.x;      // 0..63

    const int r31 = lane & 31;
    const int g2  = lane >> 5;        // 0..1

    // Staging: round = 64 rows x 64 B = 4 KB = 256 thr x 16 B.
    const int srow   = tid >> 2;                  // 0..63
    const int schunk = (tid & 3) ^ ((srow >> 1) & 3);
    const unsigned char* gA_t = A + ((size_t)(tm * 256 + srow) << 10) + schunk * 16;
    const unsigned char* gB_t = B + ((size_t)(tn * 128 + srow) << 10) + schunk * 16;

#define STAGE_A(kt, r) gload_lds16(gA_t + (((size_t)(r) * 64) << 10) + (kt) * 64, \
                                   As[(kt) & 1] + (r) * 4096 + tid * 16)
#define STAGE_B(kt, r) gload_lds16(gB_t + (((size_t)(r) * 64) << 10) + (kt) * 64, \
                                   Bs[(kt) & 1] + (r) * 4096 + tid * 16)

    f32x16 acc[4][2];   // [32-row block mi][32-col block ni]
#pragma unroll
    for (int mi = 0; mi < 4; ++mi)
#pragma unroll
        for (int ni = 0; ni < 2; ++ni)
#pragma unroll
            for (int r = 0; r < 16; ++r)
                acc[mi][ni][r] = 0.f;

    // Prologue: stage tile 0 (6 gloads).
    STAGE_A(0, 0); STAGE_A(0, 1); STAGE_A(0, 2); STAGE_A(0, 3);
    STAGE_B(0, 0); STAGE_B(0, 1);

    // o0 is fragment-independent: 32-row strides are 0 mod 4 after >>1.
    const int o0 = ((g2 * 2) ^ ((r31 >> 1) & 3)) * 16;
    const int ArBase = (wr * 128 + r31) * 64;    // + mi*32*64
    const int BrBase = (wc * 64 + r31) * 64;     // + ni*32*64

#define SB __builtin_amdgcn_sched_barrier(0)

#define MFMA2(MI, AF)                                                       \
    __builtin_amdgcn_s_setprio(1);                                          \
    acc[MI][0] = __builtin_amdgcn_mfma_scale_f32_32x32x64_f8f6f4(           \
        AF, bg0, acc[MI][0], 0, 0, 0, 127, 0, 127);                         \
    acc[MI][1] = __builtin_amdgcn_mfma_scale_f32_32x32x64_f8f6f4(           \
        AF, bg1, acc[MI][1], 0, 0, 0, 127, 0, 127);                         \
    __builtin_amdgcn_s_setprio(0);

#pragma unroll 2
    for (int kt = 0; kt < 16; ++kt) {
        const char* Ab = As[kt & 1];
        const char* Bb = Bs[kt & 1];

        // ---- per-tile gate: loads are one full tile old -> near-free ----
        asm volatile("s_waitcnt vmcnt(0)" ::: "memory");
        __builtin_amdgcn_s_barrier();
        SB;
        if (kt < 15) {
            STAGE_A(kt + 1, 0); STAGE_A(kt + 1, 1);
            STAGE_A(kt + 1, 2); STAGE_A(kt + 1, 3);
            STAGE_B(kt + 1, 0); STAGE_B(kt + 1, 1);
        }
        SB;
        i32x8 bg0 = rd32(Bb + BrBase, o0);
        i32x8 bg1 = rd32(Bb + BrBase + 2048, o0);
        i32x8 afA = rd32(Ab + ArBase, o0);
        i32x8 afB = rd32(Ab + ArBase + 2048, o0);
        MFMA2(0, afA)
        afA = rd32(Ab + ArBase + 4096, o0);
        MFMA2(1, afB)
        afB = rd32(Ab + ArBase + 6144, o0);
        MFMA2(2, afA)
        MFMA2(3, afB)
    }
#undef STAGE_A
#undef STAGE_B
#undef MFMA2
#undef SB

    // Fused reduction per 64x64 (b,t) cell (r10-verified layout).
    // C/D: col = lane&31, row = (reg&3) + 8*(reg>>2) + 4*(lane>>5).
#pragma unroll
    for (int h = 0; h < 2; ++h) {
        float cm[2];
#pragma unroll
        for (int ni = 0; ni < 2; ++ni) {
            float m = acc[h * 2][ni][0];
#pragma unroll
            for (int dm = 0; dm < 2; ++dm)
#pragma unroll
                for (int r = 0; r < 16; ++r)
                    m = fmaxf(m, acc[h * 2 + dm][ni][r]);
            m = fmaxf(m, __shfl_xor(m, 32));   // other 16 rows of the 32-row tile
            cm[ni] = m;                        // col max, replicated over lane>>5
        }
        float s = cm[0] + cm[1];
        s += __shfl_xor(s, 1);
        s += __shfl_xor(s, 2);
        s += __shfl_xor(s, 4);
        s += __shfl_xor(s, 8);
        s += __shfl_xor(s, 16);
        if (lane == 0) {
            int b = tm * 4 + wr * 2 + h;
            int t = tn * 2 + wc;
            aggr[b * 128 + t] = s;
        }
    }
}

// ---------------------------------------------------------------------------
__global__ void loss_kernel(const float* __restrict__ aggr, float* __restrict__ out)
{
    __shared__ float red[128];
    const int x = threadIdx.x;
    const float diag = aggr[x * 128 + x];
    float mrow = 0.f, mcol = 0.f;
    for (int y = 0; y < 128; ++y) {
        if (y == x) continue;
        float a_xy = aggr[x * 128 + y];
        float a_yx = aggr[y * 128 + x];
        mrow = fmaxf(mrow, 0.2f + a_xy - diag);
        mcol = fmaxf(mcol, 0.2f + a_yx - diag);
    }
    red[x] = mrow + mcol;
    __syncthreads();
    if (x == 0) {
        float s = 0.f;
        for (int i = 0; i < 128; ++i) s += red[i];
        *out = s;
    }
}

// ---------------------------------------------------------------------------
extern "C" void kernel_launch(void* const* d_in, const int* in_sizes, int n_in,
                              void* d_out, int out_size, void* d_ws, size_t ws_size,
                              hipStream_t stream)
{
    const float* im_set = (const float*)d_in[0];
    const float* s_seq  = (const float*)d_in[1];
    const int*   im_len = (const int*)d_in[2];
    const int*   s_len  = (const int*)d_in[3];
    float* out = (float*)d_out;

    unsigned char* Abf = (unsigned char*)d_ws;                          // 8 MiB
    unsigned char* Bbf = (unsigned char*)d_ws + (8u << 20);             // 8 MiB
    float*         agg = (float*)((char*)d_ws + (16u << 20));           // 64 KiB

    conv_kernel<<<16384, 256, 0, stream>>>(im_set, im_len, s_seq, s_len, Abf, Bbf);

    gemm_aggr_kernel<<<dim3(64, 32), 256, 0, stream>>>(Abf, Bbf, agg);

    loss_kernel<<<1, 128, 0, stream>>>(agg, out);
}

// Round 13
// 104.419 us; speedup vs baseline: 1.4682x; 1.0418x over previous
//
#include <hip/hip_runtime.h>
#include <hip/hip_fp8.h>

typedef __attribute__((ext_vector_type(4))) int   i32x4;
typedef __attribute__((ext_vector_type(8))) int   i32x8;
typedef __attribute__((ext_vector_type(16))) float f32x16;

// ---------------------------------------------------------------------------
// Fused slice + convert(f32 -> fp8 e4m3 OCP) + mask-zero for BOTH inputs.
__global__ void conv_kernel(const float* __restrict__ im, const int* __restrict__ iml,
                            const float* __restrict__ ss, const int* __restrict__ sl,
                            unsigned char* __restrict__ Ad, unsigned char* __restrict__ Bd)
{
    int bid = blockIdx.x;
    const float* src; const int* len; unsigned char* dst; int rawL, adj;
    if (bid < 8192) { src = im; len = iml; dst = Ad; rawL = 65; adj = -1; }
    else { bid -= 8192; src = ss; len = sl; dst = Bd; rawL = 67; adj = -3; }
    int m = bid;
    int c = threadIdx.x << 2;
    int b = m >> 6;
    int i = m & 63;
    int lim = len[b] + adj;
    float4 v;
    if (i < lim) {
        v = *(const float4*)(src + ((size_t)(b * rawL + 1 + i) << 10) + c);
    } else {
        v = make_float4(0.f, 0.f, 0.f, 0.f);
    }
    uchar4 o;
    o.x = __hip_cvt_float_to_fp8(v.x, __HIP_SATFINITE, __HIP_E4M3);
    o.y = __hip_cvt_float_to_fp8(v.y, __HIP_SATFINITE, __HIP_E4M3);
    o.z = __hip_cvt_float_to_fp8(v.z, __HIP_SATFINITE, __HIP_E4M3);
    o.w = __hip_cvt_float_to_fp8(v.w, __HIP_SATFINITE, __HIP_E4M3);
    *(uchar4*)(dst + ((size_t)m << 10) + c) = o;
}

// ---------------------------------------------------------------------------
__device__ __forceinline__ void gload_lds16(const void* g, void* l) {
    __builtin_amdgcn_global_load_lds((const __attribute__((address_space(1))) void*)g,
                                     (__attribute__((address_space(3))) void*)l,
                                     16, 0, 0);
}

// Read a 32-byte fp8 fragment as two XOR-swizzled b128 granules.
__device__ __forceinline__ i32x8 rd32(const char* base, int o0) {
    i32x4 a = *(const i32x4*)(base + o0);
    i32x4 b = *(const i32x4*)(base + (o0 ^ 16));
    return __builtin_shufflevector(a, b, 0, 1, 2, 3, 4, 5, 6, 7);
}

// 256x256 tile, BK=64 (fp8: 64B rows), 8 waves (2M x 4N), per-wave 128x64.
// RING-4 LDS (128 KiB) + REGISTER-DOUBLE-BUFFERED fragments: tile kt's MFMAs
// consume fragments prefetched during kt-1, so NO intra-tile lgkm dependency
// exists -- the wave issues {stage(kt+3), prefetch(kt+1) ds_reads, MFMA(kt)}
// as independent streams and the LDS + MFMA pipes overlap structurally.
// Per-body end gate: vmcnt(4) drains stage(kt+2) (1 body old, ~free), then
// s_barrier -> next body's prefetch of slot (kt+2)&3 is cross-wave safe.
// Write-safety: stage(kt+3) overwrites slot read during body(kt-2), 2
// barriers back. MFMA: mfma_scale_f32_32x32x64_f8f6f4, e4m3, scale=1 (127).
// C/D (r10-verified): col=lane&31, row=(reg&3)+8*(reg>>2)+4*(lane>>5).
__global__ void __launch_bounds__(512) gemm_aggr_kernel(const unsigned char* __restrict__ A,
                                                        const unsigned char* __restrict__ B,
                                                        float* __restrict__ aggr)
{
    __shared__ __align__(16) char As[4][16384];   // 256 rows x 64 B per slot
    __shared__ __align__(16) char Bs[4][16384];

    const int tid  = threadIdx.x;
    const int lane = tid & 63;
    const int wid  = tid >> 6;        // 0..7
    const int wr   = wid >> 2;        // 0..1 : 128-row half of BM=256
    const int wc   = wid & 3;         // 0..3 : 64-col quarter of BN=256
    const int tm   = blockIdx.y;      // 0..31
    const int tn   = blockIdx.x;      // 0..31

    const int r31 = lane & 31;
    const int g2  = lane >> 5;        // 0..1

    // Staging: round = 128 rows x 64 B = 8 KB = 512 thr x 16 B; 2 rounds each.
    // LDS dest linear; global source granule pre-swizzled (both-sides XOR).
    const int srow   = tid >> 2;                  // 0..127
    const int schunk = (tid & 3) ^ ((srow >> 1) & 3);
    const unsigned char* gA_t = A + ((size_t)(tm * 256 + srow) << 10) + schunk * 16;
    const unsigned char* gB_t = B + ((size_t)(tn * 256 + srow) << 10) + schunk * 16;

#define STAGE_A(kt, r) gload_lds16(gA_t + (((size_t)(r) * 128) << 10) + (kt) * 64, \
                                   As[(kt) & 3] + (r) * 8192 + tid * 16)
#define STAGE_B(kt, r) gload_lds16(gB_t + (((size_t)(r) * 128) << 10) + (kt) * 64, \
                                   Bs[(kt) & 3] + (r) * 8192 + tid * 16)

    f32x16 acc[4][2];   // [32-row block mi][32-col block ni]
#pragma unroll
    for (int mi = 0; mi < 4; ++mi)
#pragma unroll
        for (int ni = 0; ni < 2; ++ni)
#pragma unroll
            for (int r = 0; r < 16; ++r)
                acc[mi][ni][r] = 0.f;

    // o0: lane's first granule position (data granule 2*g2, key (r31>>1)&3).
    const int o0 = ((g2 * 2) ^ ((r31 >> 1) & 3)) * 16;
    const int aRow = (wr * 128 + r31) * 64;   // + mi*32*64
    const int bRow = (wc * 64 + r31) * 64;    // + ni*32*64

    i32x8 fa0[4], fb0[2], fa1[4], fb1[2];

    // Prologue: stage tiles 0,1,2; sync tiles 0,1; prefetch f0 -> (fa0,fb0).
    STAGE_A(0, 0); STAGE_A(0, 1); STAGE_B(0, 0); STAGE_B(0, 1);
    STAGE_A(1, 0); STAGE_A(1, 1); STAGE_B(1, 0); STAGE_B(1, 1);
    STAGE_A(2, 0); STAGE_A(2, 1); STAGE_B(2, 0); STAGE_B(2, 1);
    asm volatile("s_waitcnt vmcnt(4)" ::: "memory");   // tiles 0,1 landed
    __builtin_amdgcn_s_barrier();
    __builtin_amdgcn_sched_barrier(0);
    {
        const char* A0 = As[0]; const char* B0 = Bs[0];
#pragma unroll
        for (int mi = 0; mi < 4; ++mi) fa0[mi] = rd32(A0 + aRow + mi * 2048, o0);
#pragma unroll
        for (int ni = 0; ni < 2; ++ni) fb0[ni] = rd32(B0 + bRow + ni * 2048, o0);
    }

#define MFMA8(CA, CB)                                                       \
    __builtin_amdgcn_s_setprio(1);                                          \
    acc[0][0] = __builtin_amdgcn_mfma_scale_f32_32x32x64_f8f6f4(            \
        CA[0], CB[0], acc[0][0], 0, 0, 0, 127, 0, 127);                     \
    acc[0][1] = __builtin_amdgcn_mfma_scale_f32_32x32x64_f8f6f4(            \
        CA[0], CB[1], acc[0][1], 0, 0, 0, 127, 0, 127);                     \
    acc[1][0] = __builtin_amdgcn_mfma_scale_f32_32x32x64_f8f6f4(            \
        CA[1], CB[0], acc[1][0], 0, 0, 0, 127, 0, 127);                     \
    acc[1][1] = __builtin_amdgcn_mfma_scale_f32_32x32x64_f8f6f4(            \
        CA[1], CB[1], acc[1][1], 0, 0, 0, 127, 0, 127);                     \
    acc[2][0] = __builtin_amdgcn_mfma_scale_f32_32x32x64_f8f6f4(            \
        CA[2], CB[0], acc[2][0], 0, 0, 0, 127, 0, 127);                     \
    acc[2][1] = __builtin_amdgcn_mfma_scale_f32_32x32x64_f8f6f4(            \
        CA[2], CB[1], acc[2][1], 0, 0, 0, 127, 0, 127);                     \
    acc[3][0] = __builtin_amdgcn_mfma_scale_f32_32x32x64_f8f6f4(            \
        CA[3], CB[0], acc[3][0], 0, 0, 0, 127, 0, 127);                     \
    acc[3][1] = __builtin_amdgcn_mfma_scale_f32_32x32x64_f8f6f4(            \
        CA[3], CB[1], acc[3][1], 0, 0, 0, 127, 0, 127);                     \
    __builtin_amdgcn_s_setprio(0);

#define BODY(KT, CA, CB, NA, NB)                                            \
  {                                                                         \
    if ((KT) + 3 <= 15) {                                                   \
        STAGE_A((KT) + 3, 0); STAGE_A((KT) + 3, 1);                         \
        STAGE_B((KT) + 3, 0); STAGE_B((KT) + 3, 1);                         \
    }                                                                       \
    if ((KT) < 15) {                                                        \
        const char* An = As[((KT) + 1) & 3];                                \
        const char* Bn = Bs[((KT) + 1) & 3];                                \
        NA[0] = rd32(An + aRow, o0);                                        \
        NA[1] = rd32(An + aRow + 2048, o0);                                 \
        NA[2] = rd32(An + aRow + 4096, o0);                                 \
        NA[3] = rd32(An + aRow + 6144, o0);                                 \
        NB[0] = rd32(Bn + bRow, o0);                                        \
        NB[1] = rd32(Bn + bRow + 2048, o0);                                 \
    }                                                                       \
    MFMA8(CA, CB)                                                           \
    if ((KT) < 15) {                                                        \
        if ((KT) <= 12) { asm volatile("s_waitcnt vmcnt(4)" ::: "memory"); }\
        else            { asm volatile("s_waitcnt vmcnt(0)" ::: "memory"); }\
        __builtin_amdgcn_s_barrier();                                       \
        __builtin_amdgcn_sched_barrier(0);                                  \
    }                                                                       \
  }

    for (int kt2 = 0; kt2 < 8; ++kt2) {
        BODY(kt2 * 2,     fa0, fb0, fa1, fb1);
        BODY(kt2 * 2 + 1, fa1, fb1, fa0, fb0);
    }
#undef STAGE_A
#undef STAGE_B
#undef MFMA8
#undef BODY

    // Fused reduction per 64x64 (b,t) cell (r10-verified layout).
    // C/D: col = lane&31, row = (reg&3) + 8*(reg>>2) + 4*(lane>>5).
#pragma unroll
    for (int h = 0; h < 2; ++h) {
        float cm[2];
#pragma unroll
        for (int ni = 0; ni < 2; ++ni) {
            float m = acc[h * 2][ni][0];
#pragma unroll
            for (int dm = 0; dm < 2; ++dm)
#pragma unroll
                for (int r = 0; r < 16; ++r)
                    m = fmaxf(m, acc[h * 2 + dm][ni][r]);
            m = fmaxf(m, __shfl_xor(m, 32));   // other 16 rows of the 32-row tile
            cm[ni] = m;                        // col max, replicated over lane>>5
        }
        float s = cm[0] + cm[1];
        s += __shfl_xor(s, 1);
        s += __shfl_xor(s, 2);
        s += __shfl_xor(s, 4);
        s += __shfl_xor(s, 8);
        s += __shfl_xor(s, 16);
        if (lane == 0) {
            int b = tm * 4 + wr * 2 + h;
            int t = tn * 4 + wc;
            aggr[b * 128 + t] = s;
        }
    }
}

// ---------------------------------------------------------------------------
__global__ void loss_kernel(const float* __restrict__ aggr, float* __restrict__ out)
{
    __shared__ float red[128];
    const int x = threadIdx.x;
    const float diag = aggr[x * 128 + x];
    float mrow = 0.f, mcol = 0.f;
    for (int y = 0; y < 128; ++y) {
        if (y == x) continue;
        float a_xy = aggr[x * 128 + y];
        float a_yx = aggr[y * 128 + x];
        mrow = fmaxf(mrow, 0.2f + a_xy - diag);
        mcol = fmaxf(mcol, 0.2f + a_yx - diag);
    }
    red[x] = mrow + mcol;
    __syncthreads();
    if (x == 0) {
        float s = 0.f;
        for (int i = 0; i < 128; ++i) s += red[i];
        *out = s;
    }
}

// ---------------------------------------------------------------------------
extern "C" void kernel_launch(void* const* d_in, const int* in_sizes, int n_in,
                              void* d_out, int out_size, void* d_ws, size_t ws_size,
                              hipStream_t stream)
{
    const float* im_set = (const float*)d_in[0];
    const float* s_seq  = (const float*)d_in[1];
    const int*   im_len = (const int*)d_in[2];
    const int*   s_len  = (const int*)d_in[3];
    float* out = (float*)d_out;

    unsigned char* Abf = (unsigned char*)d_ws;                          // 8 MiB
    unsigned char* Bbf = (unsigned char*)d_ws + (8u << 20);             // 8 MiB
    float*         agg = (float*)((char*)d_ws + (16u << 20));           // 64 KiB

    conv_kernel<<<16384, 256, 0, stream>>>(im_set, im_len, s_seq, s_len, Abf, Bbf);

    gemm_aggr_kernel<<<dim3(32, 32), 512, 0, stream>>>(Abf, Bbf, agg);

    loss_kernel<<<1, 128, 0, stream>>>(agg, out);
}

// Round 14
// 94.436 us; speedup vs baseline: 1.6235x; 1.1057x over previous
//
#include <hip/hip_runtime.h>
#include <hip/hip_fp8.h>

typedef __attribute__((ext_vector_type(4))) int   i32x4;
typedef __attribute__((ext_vector_type(8))) int   i32x8;
typedef __attribute__((ext_vector_type(16))) float f32x16;

// ---------------------------------------------------------------------------
// Fused slice + convert(f32 -> fp8 e4m3 OCP) + mask-zero for BOTH inputs.
__global__ void conv_kernel(const float* __restrict__ im, const int* __restrict__ iml,
                            const float* __restrict__ ss, const int* __restrict__ sl,
                            unsigned char* __restrict__ Ad, unsigned char* __restrict__ Bd)
{
    int bid = blockIdx.x;
    const float* src; const int* len; unsigned char* dst; int rawL, adj;
    if (bid < 8192) { src = im; len = iml; dst = Ad; rawL = 65; adj = -1; }
    else { bid -= 8192; src = ss; len = sl; dst = Bd; rawL = 67; adj = -3; }
    int m = bid;
    int c = threadIdx.x << 2;
    int b = m >> 6;
    int i = m & 63;
    int lim = len[b] + adj;
    float4 v;
    if (i < lim) {
        v = *(const float4*)(src + ((size_t)(b * rawL + 1 + i) << 10) + c);
    } else {
        v = make_float4(0.f, 0.f, 0.f, 0.f);
    }
    uchar4 o;
    o.x = __hip_cvt_float_to_fp8(v.x, __HIP_SATFINITE, __HIP_E4M3);
    o.y = __hip_cvt_float_to_fp8(v.y, __HIP_SATFINITE, __HIP_E4M3);
    o.z = __hip_cvt_float_to_fp8(v.z, __HIP_SATFINITE, __HIP_E4M3);
    o.w = __hip_cvt_float_to_fp8(v.w, __HIP_SATFINITE, __HIP_E4M3);
    *(uchar4*)(dst + ((size_t)m << 10) + c) = o;
}

// ---------------------------------------------------------------------------
__device__ __forceinline__ void gload_lds16(const void* g, void* l) {
    __builtin_amdgcn_global_load_lds((const __attribute__((address_space(1))) void*)g,
                                     (__attribute__((address_space(3))) void*)l,
                                     16, 0, 0);
}

// Contiguous fragment read: two b128 at +0 and +128 (granules 2g2, 2g2+1).
__device__ __forceinline__ i32x8 rd32c(const char* base) {
    i32x4 a = *(const i32x4*)(base);
    i32x4 b = *(const i32x4*)(base + 128);
    return __builtin_shufflevector(a, b, 0, 1, 2, 3, 4, 5, 6, 7);
}

// 256x256 tile, BK=64 (fp8), 8 waves (2M x 4N), per-wave 128x64, ring-4 LDS
// (128 KiB) + register-double-buffered fragments (r13 schedule, verified).
// NEW: fragment-major LDS layout, NO swizzle:
//   pos16(row, g) = (row>>3)*32 + g*8 + (row&7)   (g = 16B k-granule 0..3)
// -> every 8-lane b128 read group touches stride-16 consecutive bytes
//    (canonical zero-bank-conflict), and global_load_lds staging of this
//    layout is fully coalesced (each wave consumes 16 whole 64B lines).
// Ledger (r13): body(kt) = {stage(kt+3), prefetch(kt+1) reads, MFMA(kt),
// vmcnt(4) [kt<=12, drains kt+2's stage] else vmcnt(0), s_barrier}.
// MFMA: mfma_scale_f32_32x32x64_f8f6f4, e4m3, scale=1 (E8M0 127).
// C/D (r10-verified): col=lane&31, row=(reg&3)+8*(reg>>2)+4*(lane>>5).
__global__ void __launch_bounds__(512) gemm_aggr_kernel(const unsigned char* __restrict__ A,
                                                        const unsigned char* __restrict__ B,
                                                        float* __restrict__ aggr)
{
    __shared__ __align__(16) char As[4][16384];   // 256 rows x 64 B per slot
    __shared__ __align__(16) char Bs[4][16384];

    const int tid  = threadIdx.x;
    const int lane = tid & 63;
    const int wid  = tid >> 6;        // 0..7
    const int wr   = wid >> 2;        // 0..1 : 128-row half of BM=256
    const int wc   = wid & 3;         // 0..3 : 64-col quarter of BN=256
    const int tm   = blockIdx.y;      // 0..31
    const int tn   = blockIdx.x;      // 0..31

    const int r31 = lane & 31;
    const int g2  = lane >> 5;        // 0..1

    // Staging: linear LDS pos ℓ = round*512 + tid maps to
    //   row = ((ℓ>>5)<<3)|(ℓ&7), granule g = (ℓ>>3)&3  (round adds 128 rows).
    const int srow0 = ((tid >> 5) << 3) | (tid & 7);   // 0..127
    const int sgran = (tid >> 3) & 3;
    const unsigned char* gA_t = A + ((size_t)(tm * 256 + srow0) << 10) + sgran * 16;
    const unsigned char* gB_t = B + ((size_t)(tn * 256 + srow0) << 10) + sgran * 16;

#define STAGE_A(kt, r) gload_lds16(gA_t + (((size_t)(r) * 128) << 10) + (kt) * 64, \
                                   As[(kt) & 3] + (r) * 8192 + tid * 16)
#define STAGE_B(kt, r) gload_lds16(gB_t + (((size_t)(r) * 128) << 10) + (kt) * 64, \
                                   Bs[(kt) & 3] + (r) * 8192 + tid * 16)

    f32x16 acc[4][2];   // [32-row block mi][32-col block ni]
#pragma unroll
    for (int mi = 0; mi < 4; ++mi)
#pragma unroll
        for (int ni = 0; ni < 2; ++ni)
#pragma unroll
            for (int r = 0; r < 16; ++r)
                acc[mi][ni][r] = 0.f;

    // Fragment byte bases within a slot (fragment-major layout):
    // byte(row,g) = (row>>3)*512 + g*128 + (row&7)*16 ; row = base + mi*32 + r31.
    const int fOff = ((r31 >> 3) << 9) + g2 * 256 + (r31 & 7) * 16;
    const int aOff = wr * 8192 + fOff;    // + mi*2048
    const int bOff = wc * 4096 + fOff;    // + ni*2048

    i32x8 fa0[4], fb0[2], fa1[4], fb1[2];

    // Prologue: stage tiles 0,1,2; sync tiles 0,1; prefetch tile 0 fragments.
    STAGE_A(0, 0); STAGE_A(0, 1); STAGE_B(0, 0); STAGE_B(0, 1);
    STAGE_A(1, 0); STAGE_A(1, 1); STAGE_B(1, 0); STAGE_B(1, 1);
    STAGE_A(2, 0); STAGE_A(2, 1); STAGE_B(2, 0); STAGE_B(2, 1);
    asm volatile("s_waitcnt vmcnt(4)" ::: "memory");   // tiles 0,1 landed
    __builtin_amdgcn_s_barrier();
    __builtin_amdgcn_sched_barrier(0);
    {
        const char* A0 = As[0]; const char* B0 = Bs[0];
#pragma unroll
        for (int mi = 0; mi < 4; ++mi) fa0[mi] = rd32c(A0 + aOff + mi * 2048);
#pragma unroll
        for (int ni = 0; ni < 2; ++ni) fb0[ni] = rd32c(B0 + bOff + ni * 2048);
    }

#define MFMA8(CA, CB)                                                       \
    __builtin_amdgcn_s_setprio(1);                                          \
    acc[0][0] = __builtin_amdgcn_mfma_scale_f32_32x32x64_f8f6f4(            \
        CA[0], CB[0], acc[0][0], 0, 0, 0, 127, 0, 127);                     \
    acc[0][1] = __builtin_amdgcn_mfma_scale_f32_32x32x64_f8f6f4(            \
        CA[0], CB[1], acc[0][1], 0, 0, 0, 127, 0, 127);                     \
    acc[1][0] = __builtin_amdgcn_mfma_scale_f32_32x32x64_f8f6f4(            \
        CA[1], CB[0], acc[1][0], 0, 0, 0, 127, 0, 127);                     \
    acc[1][1] = __builtin_amdgcn_mfma_scale_f32_32x32x64_f8f6f4(            \
        CA[1], CB[1], acc[1][1], 0, 0, 0, 127, 0, 127);                     \
    acc[2][0] = __builtin_amdgcn_mfma_scale_f32_32x32x64_f8f6f4(            \
        CA[2], CB[0], acc[2][0], 0, 0, 0, 127, 0, 127);                     \
    acc[2][1] = __builtin_amdgcn_mfma_scale_f32_32x32x64_f8f6f4(            \
        CA[2], CB[1], acc[2][1], 0, 0, 0, 127, 0, 127);                     \
    acc[3][0] = __builtin_amdgcn_mfma_scale_f32_32x32x64_f8f6f4(            \
        CA[3], CB[0], acc[3][0], 0, 0, 0, 127, 0, 127);                     \
    acc[3][1] = __builtin_amdgcn_mfma_scale_f32_32x32x64_f8f6f4(            \
        CA[3], CB[1], acc[3][1], 0, 0, 0, 127, 0, 127);                     \
    __builtin_amdgcn_s_setprio(0);

#define BODY(KT, CA, CB, NA, NB)                                            \
  {                                                                         \
    if ((KT) + 3 <= 15) {                                                   \
        STAGE_A((KT) + 3, 0); STAGE_A((KT) + 3, 1);                         \
        STAGE_B((KT) + 3, 0); STAGE_B((KT) + 3, 1);                         \
    }                                                                       \
    if ((KT) < 15) {                                                        \
        const char* An = As[((KT) + 1) & 3];                                \
        const char* Bn = Bs[((KT) + 1) & 3];                                \
        NA[0] = rd32c(An + aOff);                                           \
        NA[1] = rd32c(An + aOff + 2048);                                    \
        NA[2] = rd32c(An + aOff + 4096);                                    \
        NA[3] = rd32c(An + aOff + 6144);                                    \
        NB[0] = rd32c(Bn + bOff);                                           \
        NB[1] = rd32c(Bn + bOff + 2048);                                    \
    }                                                                       \
    MFMA8(CA, CB)                                                           \
    if ((KT) < 15) {                                                        \
        if ((KT) <= 12) { asm volatile("s_waitcnt vmcnt(4)" ::: "memory"); }\
        else            { asm volatile("s_waitcnt vmcnt(0)" ::: "memory"); }\
        __builtin_amdgcn_s_barrier();                                       \
        __builtin_amdgcn_sched_barrier(0);                                  \
    }                                                                       \
  }

    for (int kt2 = 0; kt2 < 8; ++kt2) {
        BODY(kt2 * 2,     fa0, fb0, fa1, fb1);
        BODY(kt2 * 2 + 1, fa1, fb1, fa0, fb0);
    }
#undef STAGE_A
#undef STAGE_B
#undef MFMA8
#undef BODY

    // Fused reduction per 64x64 (b,t) cell (r10-verified layout).
    // C/D: col = lane&31, row = (reg&3) + 8*(reg>>2) + 4*(lane>>5).
#pragma unroll
    for (int h = 0; h < 2; ++h) {
        float cm[2];
#pragma unroll
        for (int ni = 0; ni < 2; ++ni) {
            float m = acc[h * 2][ni][0];
#pragma unroll
            for (int dm = 0; dm < 2; ++dm)
#pragma unroll
                for (int r = 0; r < 16; ++r)
                    m = fmaxf(m, acc[h * 2 + dm][ni][r]);
            m = fmaxf(m, __shfl_xor(m, 32));   // other 16 rows of the 32-row tile
            cm[ni] = m;                        // col max, replicated over lane>>5
        }
        float s = cm[0] + cm[1];
        s += __shfl_xor(s, 1);
        s += __shfl_xor(s, 2);
        s += __shfl_xor(s, 4);
        s += __shfl_xor(s, 8);
        s += __shfl_xor(s, 16);
        if (lane == 0) {
            int b = tm * 4 + wr * 2 + h;
            int t = tn * 4 + wc;
            aggr[b * 128 + t] = s;
        }
    }
}

// ---------------------------------------------------------------------------
// Parallel loss: stage 1 = one block per x (128 threads over y), stage 2 = sum.
__global__ void loss_stage1(const float* __restrict__ aggr, float* __restrict__ red)
{
    const int x = blockIdx.x;
    const int y = threadIdx.x;
    const float diag = aggr[x * 129];
    float ms = 0.f, mi = 0.f;
    if (y != x) {
        ms = fmaxf(0.2f + aggr[x * 128 + y] - diag, 0.f);
        mi = fmaxf(0.2f + aggr[y * 128 + x] - diag, 0.f);
    }
#pragma unroll
    for (int o = 32; o; o >>= 1) {
        ms = fmaxf(ms, __shfl_xor(ms, o));
        mi = fmaxf(mi, __shfl_xor(mi, o));
    }
    __shared__ float sm[2], si[2];
    if ((y & 63) == 0) { sm[y >> 6] = ms; si[y >> 6] = mi; }
    __syncthreads();
    if (y == 0) red[x] = fmaxf(sm[0], sm[1]) + fmaxf(si[0], si[1]);
}

__global__ void loss_stage2(const float* __restrict__ red, float* __restrict__ out)
{
    float v = red[threadIdx.x];
#pragma unroll
    for (int o = 32; o; o >>= 1) v += __shfl_xor(v, o);
    __shared__ float s[2];
    if ((threadIdx.x & 63) == 0) s[threadIdx.x >> 6] = v;
    __syncthreads();
    if (threadIdx.x == 0) *out = s[0] + s[1];
}

// ---------------------------------------------------------------------------
extern "C" void kernel_launch(void* const* d_in, const int* in_sizes, int n_in,
                              void* d_out, int out_size, void* d_ws, size_t ws_size,
                              hipStream_t stream)
{
    const float* im_set = (const float*)d_in[0];
    const float* s_seq  = (const float*)d_in[1];
    const int*   im_len = (const int*)d_in[2];
    const int*   s_len  = (const int*)d_in[3];
    float* out = (float*)d_out;

    unsigned char* Abf = (unsigned char*)d_ws;                          // 8 MiB
    unsigned char* Bbf = (unsigned char*)d_ws + (8u << 20);             // 8 MiB
    float*         agg = (float*)((char*)d_ws + (16u << 20));           // 64 KiB
    float*         red = (float*)((char*)d_ws + (16u << 20) + 65536);   // 512 B

    conv_kernel<<<16384, 256, 0, stream>>>(im_set, im_len, s_seq, s_len, Abf, Bbf);

    gemm_aggr_kernel<<<dim3(32, 32), 512, 0, stream>>>(Abf, Bbf, agg);

    loss_stage1<<<128, 128, 0, stream>>>(agg, red);
    loss_stage2<<<1, 128, 0, stream>>>(red, out);
}

// Round 15
// 79.644 us; speedup vs baseline: 1.9250x; 1.1857x over previous
//
#include <hip/hip_runtime.h>
#include <hip/hip_fp8.h>

typedef __attribute__((ext_vector_type(4))) int   i32x4;
typedef __attribute__((ext_vector_type(8))) int   i32x8;
typedef __attribute__((ext_vector_type(16))) float f32x16;

// ---------------------------------------------------------------------------
// Fused slice + convert(f32 -> fp8 e4m3 OCP) + mask-zero for BOTH inputs.
__global__ void conv_kernel(const float* __restrict__ im, const int* __restrict__ iml,
                            const float* __restrict__ ss, const int* __restrict__ sl,
                            unsigned char* __restrict__ Ad, unsigned char* __restrict__ Bd)
{
    int bid = blockIdx.x;
    const float* src; const int* len; unsigned char* dst; int rawL, adj;
    if (bid < 8192) { src = im; len = iml; dst = Ad; rawL = 65; adj = -1; }
    else { bid -= 8192; src = ss; len = sl; dst = Bd; rawL = 67; adj = -3; }
    int m = bid;
    int c = threadIdx.x << 2;
    int b = m >> 6;
    int i = m & 63;
    int lim = len[b] + adj;
    float4 v;
    if (i < lim) {
        v = *(const float4*)(src + ((size_t)(b * rawL + 1 + i) << 10) + c);
    } else {
        v = make_float4(0.f, 0.f, 0.f, 0.f);
    }
    uchar4 o;
    o.x = __hip_cvt_float_to_fp8(v.x, __HIP_SATFINITE, __HIP_E4M3);
    o.y = __hip_cvt_float_to_fp8(v.y, __HIP_SATFINITE, __HIP_E4M3);
    o.z = __hip_cvt_float_to_fp8(v.z, __HIP_SATFINITE, __HIP_E4M3);
    o.w = __hip_cvt_float_to_fp8(v.w, __HIP_SATFINITE, __HIP_E4M3);
    *(uchar4*)(dst + ((size_t)m << 10) + c) = o;
}

// ---------------------------------------------------------------------------
__device__ __forceinline__ void gload_lds16(const void* g, void* l) {
    __builtin_amdgcn_global_load_lds((const __attribute__((address_space(1))) void*)g,
                                     (__attribute__((address_space(3))) void*)l,
                                     16, 0, 0);
}

// Read a 32-byte fp8 fragment as two XOR-swizzled b128 granules.
__device__ __forceinline__ i32x8 rd32(const char* base, int o0) {
    i32x4 a = *(const i32x4*)(base + o0);
    i32x4 b = *(const i32x4*)(base + (o0 ^ 16));
    return __builtin_shufflevector(a, b, 0, 1, 2, 3, 4, 5, 6, 7);
}

// 256x256 tile, BK=64 (fp8: 64B rows), 8 waves (2M x 4N), per-wave 128x64.
// RING-4 LDS (128 KiB) + REGISTER-DOUBLE-BUFFERED fragments (r13-verified,
// 72.9 us): tile kt's MFMAs consume fragments prefetched during kt-1 -> no
// intra-tile lgkm dependency; {stage(kt+3), prefetch(kt+1), MFMA(kt)} are
// independent streams. Per-body end gate: vmcnt(4) drains stage(kt+2)
// (1 body old, ~free) then s_barrier. Write-safety: stage(kt+3) overwrites
// the slot last read in body(kt-2), two barriers back.
// MFMA: mfma_scale_f32_32x32x64_f8f6f4, e4m3, scale=1 (E8M0 127).
// C/D (r10-verified): col=lane&31, row=(reg&3)+8*(reg>>2)+4*(lane>>5).
__global__ void __launch_bounds__(512) gemm_aggr_kernel(const unsigned char* __restrict__ A,
                                                        const unsigned char* __restrict__ B,
                                                        float* __restrict__ aggr)
{
    __shared__ __align__(16) char As[4][16384];   // 256 rows x 64 B per slot
    __shared__ __align__(16) char Bs[4][16384];

    const int tid  = threadIdx.x;
    const int lane = tid & 63;
    const int wid  = tid >> 6;        // 0..7
    const int wr   = wid >> 2;        // 0..1 : 128-row half of BM=256
    const int wc   = wid & 3;         // 0..3 : 64-col quarter of BN=256
    const int tm   = blockIdx.y;      // 0..31
    const int tn   = blockIdx.x;      // 0..31

    const int r31 = lane & 31;
    const int g2  = lane >> 5;        // 0..1

    // Staging: round = 128 rows x 64 B = 8 KB = 512 thr x 16 B; 2 rounds each.
    // LDS dest linear; global source granule pre-swizzled (both-sides XOR).
    const int srow   = tid >> 2;                  // 0..127
    const int schunk = (tid & 3) ^ ((srow >> 1) & 3);
    const unsigned char* gA_t = A + ((size_t)(tm * 256 + srow) << 10) + schunk * 16;
    const unsigned char* gB_t = B + ((size_t)(tn * 256 + srow) << 10) + schunk * 16;

#define STAGE_A(kt, r) gload_lds16(gA_t + (((size_t)(r) * 128) << 10) + (kt) * 64, \
                                   As[(kt) & 3] + (r) * 8192 + tid * 16)
#define STAGE_B(kt, r) gload_lds16(gB_t + (((size_t)(r) * 128) << 10) + (kt) * 64, \
                                   Bs[(kt) & 3] + (r) * 8192 + tid * 16)

    f32x16 acc[4][2];   // [32-row block mi][32-col block ni]
#pragma unroll
    for (int mi = 0; mi < 4; ++mi)
#pragma unroll
        for (int ni = 0; ni < 2; ++ni)
#pragma unroll
            for (int r = 0; r < 16; ++r)
                acc[mi][ni][r] = 0.f;

    // o0: lane's first granule position (data granule 2*g2, key (r31>>1)&3).
    const int o0 = ((g2 * 2) ^ ((r31 >> 1) & 3)) * 16;
    const int aRow = (wr * 128 + r31) * 64;   // + mi*32*64
    const int bRow = (wc * 64 + r31) * 64;    // + ni*32*64

    i32x8 fa0[4], fb0[2], fa1[4], fb1[2];

    // Prologue: stage tiles 0,1,2; sync tiles 0,1; prefetch f0 -> (fa0,fb0).
    STAGE_A(0, 0); STAGE_A(0, 1); STAGE_B(0, 0); STAGE_B(0, 1);
    STAGE_A(1, 0); STAGE_A(1, 1); STAGE_B(1, 0); STAGE_B(1, 1);
    STAGE_A(2, 0); STAGE_A(2, 1); STAGE_B(2, 0); STAGE_B(2, 1);
    asm volatile("s_waitcnt vmcnt(4)" ::: "memory");   // tiles 0,1 landed
    __builtin_amdgcn_s_barrier();
    __builtin_amdgcn_sched_barrier(0);
    {
        const char* A0 = As[0]; const char* B0 = Bs[0];
#pragma unroll
        for (int mi = 0; mi < 4; ++mi) fa0[mi] = rd32(A0 + aRow + mi * 2048, o0);
#pragma unroll
        for (int ni = 0; ni < 2; ++ni) fb0[ni] = rd32(B0 + bRow + ni * 2048, o0);
    }

#define MFMA8(CA, CB)                                                       \
    __builtin_amdgcn_s_setprio(1);                                          \
    acc[0][0] = __builtin_amdgcn_mfma_scale_f32_32x32x64_f8f6f4(            \
        CA[0], CB[0], acc[0][0], 0, 0, 0, 127, 0, 127);                     \
    acc[0][1] = __builtin_amdgcn_mfma_scale_f32_32x32x64_f8f6f4(            \
        CA[0], CB[1], acc[0][1], 0, 0, 0, 127, 0, 127);                     \
    acc[1][0] = __builtin_amdgcn_mfma_scale_f32_32x32x64_f8f6f4(            \
        CA[1], CB[0], acc[1][0], 0, 0, 0, 127, 0, 127);                     \
    acc[1][1] = __builtin_amdgcn_mfma_scale_f32_32x32x64_f8f6f4(            \
        CA[1], CB[1], acc[1][1], 0, 0, 0, 127, 0, 127);                     \
    acc[2][0] = __builtin_amdgcn_mfma_scale_f32_32x32x64_f8f6f4(            \
        CA[2], CB[0], acc[2][0], 0, 0, 0, 127, 0, 127);                     \
    acc[2][1] = __builtin_amdgcn_mfma_scale_f32_32x32x64_f8f6f4(            \
        CA[2], CB[1], acc[2][1], 0, 0, 0, 127, 0, 127);                     \
    acc[3][0] = __builtin_amdgcn_mfma_scale_f32_32x32x64_f8f6f4(            \
        CA[3], CB[0], acc[3][0], 0, 0, 0, 127, 0, 127);                     \
    acc[3][1] = __builtin_amdgcn_mfma_scale_f32_32x32x64_f8f6f4(            \
        CA[3], CB[1], acc[3][1], 0, 0, 0, 127, 0, 127);                     \
    __builtin_amdgcn_s_setprio(0);

#define BODY(KT, CA, CB, NA, NB)                                            \
  {                                                                         \
    if ((KT) + 3 <= 15) {                                                   \
        STAGE_A((KT) + 3, 0); STAGE_A((KT) + 3, 1);                         \
        STAGE_B((KT) + 3, 0); STAGE_B((KT) + 3, 1);                         \
    }                                                                       \
    if ((KT) < 15) {                                                        \
        const char* An = As[((KT) + 1) & 3];                                \
        const char* Bn = Bs[((KT) + 1) & 3];                                \
        NA[0] = rd32(An + aRow, o0);                                        \
        NA[1] = rd32(An + aRow + 2048, o0);                                 \
        NA[2] = rd32(An + aRow + 4096, o0);                                 \
        NA[3] = rd32(An + aRow + 6144, o0);                                 \
        NB[0] = rd32(Bn + bRow, o0);                                        \
        NB[1] = rd32(Bn + bRow + 2048, o0);                                 \
    }                                                                       \
    MFMA8(CA, CB)                                                           \
    if ((KT) < 15) {                                                        \
        if ((KT) <= 12) { asm volatile("s_waitcnt vmcnt(4)" ::: "memory"); }\
        else            { asm volatile("s_waitcnt vmcnt(0)" ::: "memory"); }\
        __builtin_amdgcn_s_barrier();                                       \
        __builtin_amdgcn_sched_barrier(0);                                  \
    }                                                                       \
  }

    for (int kt2 = 0; kt2 < 8; ++kt2) {
        BODY(kt2 * 2,     fa0, fb0, fa1, fb1);
        BODY(kt2 * 2 + 1, fa1, fb1, fa0, fb0);
    }
#undef STAGE_A
#undef STAGE_B
#undef MFMA8
#undef BODY

    // Fused reduction per 64x64 (b,t) cell (r10-verified layout).
    // C/D: col = lane&31, row = (reg&3) + 8*(reg>>2) + 4*(lane>>5).
#pragma unroll
    for (int h = 0; h < 2; ++h) {
        float cm[2];
#pragma unroll
        for (int ni = 0; ni < 2; ++ni) {
            float m = acc[h * 2][ni][0];
#pragma unroll
            for (int dm = 0; dm < 2; ++dm)
#pragma unroll
                for (int r = 0; r < 16; ++r)
                    m = fmaxf(m, acc[h * 2 + dm][ni][r]);
            m = fmaxf(m, __shfl_xor(m, 32));   // other 16 rows of the 32-row tile
            cm[ni] = m;                        // col max, replicated over lane>>5
        }
        float s = cm[0] + cm[1];
        s += __shfl_xor(s, 1);
        s += __shfl_xor(s, 2);
        s += __shfl_xor(s, 4);
        s += __shfl_xor(s, 8);
        s += __shfl_xor(s, 16);
        if (lane == 0) {
            int b = tm * 4 + wr * 2 + h;
            int t = tn * 4 + wc;
            aggr[b * 128 + t] = s;
        }
    }
}

// ---------------------------------------------------------------------------
// Parallel loss: stage 1 = one block per x (128 threads over y), stage 2 = sum.
__global__ void loss_stage1(const float* __restrict__ aggr, float* __restrict__ red)
{
    const int x = blockIdx.x;
    const int y = threadIdx.x;
    const float diag = aggr[x * 129];
    float ms = 0.f, mi = 0.f;
    if (y != x) {
        ms = fmaxf(0.2f + aggr[x * 128 + y] - diag, 0.f);
        mi = fmaxf(0.2f + aggr[y * 128 + x] - diag, 0.f);
    }
#pragma unroll
    for (int o = 32; o; o >>= 1) {
        ms = fmaxf(ms, __shfl_xor(ms, o));
        mi = fmaxf(mi, __shfl_xor(mi, o));
    }
    __shared__ float sm[2], si[2];
    if ((y & 63) == 0) { sm[y >> 6] = ms; si[y >> 6] = mi; }
    __syncthreads();
    if (y == 0) red[x] = fmaxf(sm[0], sm[1]) + fmaxf(si[0], si[1]);
}

__global__ void loss_stage2(const float* __restrict__ red, float* __restrict__ out)
{
    float v = red[threadIdx.x];
#pragma unroll
    for (int o = 32; o; o >>= 1) v += __shfl_xor(v, o);
    __shared__ float s[2];
    if ((threadIdx.x & 63) == 0) s[threadIdx.x >> 6] = v;
    __syncthreads();
    if (threadIdx.x == 0) *out = s[0] + s[1];
}

// ---------------------------------------------------------------------------
extern "C" void kernel_launch(void* const* d_in, const int* in_sizes, int n_in,
                              void* d_out, int out_size, void* d_ws, size_t ws_size,
                              hipStream_t stream)
{
    const float* im_set = (const float*)d_in[0];
    const float* s_seq  = (const float*)d_in[1];
    const int*   im_len = (const int*)d_in[2];
    const int*   s_len  = (const int*)d_in[3];
    float* out = (float*)d_out;

    unsigned char* Abf = (unsigned char*)d_ws;                          // 8 MiB
    unsigned char* Bbf = (unsigned char*)d_ws + (8u << 20);             // 8 MiB
    float*         agg = (float*)((char*)d_ws + (16u << 20));           // 64 KiB
    float*         red = (float*)((char*)d_ws + (16u << 20) + 65536);   // 512 B

    conv_kernel<<<16384, 256, 0, stream>>>(im_set, im_len, s_seq, s_len, Abf, Bbf);

    gemm_aggr_kernel<<<dim3(32, 32), 512, 0, stream>>>(Abf, Bbf, agg);

    loss_stage1<<<128, 128, 0, stream>>>(agg, red);
    loss_stage2<<<1, 128, 0, stream>>>(red, out);
}